// Round 4
// baseline (303.452 us; speedup 1.0000x reference)
//
#include <hip/hip_runtime.h>
#include <cstdint>

typedef unsigned short u16;
typedef unsigned int   u32;
typedef __attribute__((ext_vector_type(2))) float f32x2;
typedef __attribute__((ext_vector_type(4))) float f32x4;

__device__ __forceinline__ float bf2f(u16 u){ return __uint_as_float(((u32)u) << 16); }
__device__ __forceinline__ float bflo(u32 u){ return __uint_as_float(u << 16); }
__device__ __forceinline__ float bfhi(u32 u){ return __uint_as_float(u & 0xffff0000u); }
__device__ __forceinline__ u16 f2bf(float f){
    u32 x = __float_as_uint(f);
    u32 r = x + 0x7fffu + ((x >> 16) & 1u);
    return (u16)(r >> 16);
}
__device__ __forceinline__ int detect_bf16(const void* p){
    const u16* h = (const u16*)p;
    int hits = 0;
    for (int i = 0; i < 64; ++i){
        const int e = (h[2 * i] >> 7) & 0xFF;
        hits += (e >= 110 && e <= 140) ? 1 : 0;
    }
    return hits >= 40;
}
__device__ __forceinline__ int detect_i64(const int* p){
    int z = 0;
    for (int i = 0; i < 48; ++i) z += (p[2 * i + 1] == 0) ? 1 : 0;
    return z >= 40;
}
__device__ __forceinline__ float ldf(const void* p, size_t i, int isbf){
    return isbf ? bf2f(((const u16*)p)[i]) : ((const float*)p)[i];
}
__device__ __forceinline__ void read_proj(const int* proj, int q, int p64,
                                          int& pz, int& py, int& px){
    if (p64){
        pz = proj[(size_t)(q * 3 + 0) * 2];
        py = proj[(size_t)(q * 3 + 1) * 2];
        px = proj[(size_t)(q * 3 + 2) * 2];
    } else {
        pz = proj[q * 3 + 0]; py = proj[q * 3 + 1]; px = proj[q * 3 + 2];
    }
    pz = min(max(pz, 0), 47); py = min(max(py, 0), 47); px = min(max(px, 0), 47);
}

// packed fp32 FMA helpers (v_pk_fma_f32)
__device__ __forceinline__ void pk_fma_b0(f32x2& acc, const f32x2 s, const f32x2 m){
    asm("v_pk_fma_f32 %0, %1, %2, %0 op_sel:[0,0,0] op_sel_hi:[0,1,1]"
        : "+v"(acc) : "v"(s), "v"(m));
}
__device__ __forceinline__ void pk_fma_b1(f32x2& acc, const f32x2 s, const f32x2 m){
    asm("v_pk_fma_f32 %0, %1, %2, %0 op_sel:[1,0,0] op_sel_hi:[1,1,1]"
        : "+v"(acc) : "v"(s), "v"(m));
}
__device__ __forceinline__ void pk_fma(f32x2& acc, const f32x2 a, const f32x2 b){
    asm("v_pk_fma_f32 %0, %1, %2, %0"
        : "+v"(acc) : "v"(a), "v"(b));
}

// row-internal 16B-granule swizzle for a 128-float row: G(0..31) -> G ^ (G>>3)
// makes full-row wave reads 2-way (free) instead of 4-way banked.
__device__ __forceinline__ int gswz(int i /*float4 idx within row, 0..31*/){
    return i ^ (i >> 3);
}

// ---------------- merged prep:
// blocks 0..63 : M[e][c] = sum_d qw[d][e]*kw[d][c]  (2 e's per block); block 0 also bias+flags
// blocks 64..127: W2[c][d] = vw[d][c]
__global__ __launch_bounds__(256) void k_prep(const void* __restrict__ qw_,
                                              const void* __restrict__ qb_,
                                              const void* __restrict__ kw_,
                                              const void* __restrict__ vw_,
                                              const void* __restrict__ qf_,
                                              const void* __restrict__ feat_,
                                              const int*  __restrict__ proj_,
                                              const void* __restrict__ vb_,
                                              float* __restrict__ M,
                                              float* __restrict__ bias,
                                              float* __restrict__ W2,
                                              int* __restrict__ flags){
    const int bid = blockIdx.x, t = threadIdx.x;
    if (bid < 64){
        if (bid == 0){
            if (t == 0)      flags[0] = detect_bf16(qf_);
            else if (t == 1) flags[1] = detect_bf16(feat_);
            else if (t == 2) flags[2] = detect_bf16(vb_);
            else if (t == 3) flags[3] = detect_i64(proj_);
        }
        const int e = bid * 2 + (t >> 7), c = t & 127;
        const int is_qw = detect_bf16(qw_), is_kw = detect_bf16(kw_);
        float acc = 0.f;
        for (int d = 0; d < 128; ++d)
            acc += ldf(kw_, (size_t)d * 128 + c, is_kw) * ldf(qw_, (size_t)d * 128 + e, is_qw);
        M[e * 128 + c] = acc;
        if (bid == 0 && t < 128){
            const int is_qb = detect_bf16(qb_);
            float ab = 0.f;
            for (int d = 0; d < 128; ++d)
                ab += ldf(kw_, (size_t)d * 128 + t, is_kw) * ldf(qb_, d, is_qb);
            bias[t] = ab;
        }
    } else {
        const int i = (bid - 64) * 256 + t;   // 0..16383
        const int c = i >> 7, d = i & 127;
        const int is_vw = detect_bf16(vw_);
        W2[c * 128 + d] = ldf(vw_, (size_t)d * 128 + c, is_vw);
    }
}

// ---------------- transpose (B,C,48,48,48) -> (B,48*48*48,C) bf16, NO padding.
__global__ __launch_bounds__(256) void k_tr(const void* __restrict__ feat_,
                                            u16* __restrict__ featT,
                                            const int* __restrict__ flags){
    __shared__ u32 sh[4096];        // 64 voxels * 64 u32 (channel pairs), swizzled
    const int t = threadIdx.x;
    const int isbf = flags[1];
    const int chunk = blockIdx.x;                     // 0..3455
    const int b = chunk / 1728;
    const size_t rel = (size_t)(chunk - b * 1728) * 64;
    if (isbf){
        const u16* f = (const u16*)feat_;
        for (int it = 0; it < 4; ++it){
            const int i = it * 256 + t;               // 0..1023
            const int c2 = i >> 4, q16 = i & 15;
            const size_t sA = ((size_t)(b * 128 + 2 * c2    )) * 110592 + rel + q16 * 4;
            const size_t sB = ((size_t)(b * 128 + 2 * c2 + 1)) * 110592 + rel + q16 * 4;
            const uint2 va = *reinterpret_cast<const uint2*>(f + sA);
            const uint2 vb = *reinterpret_cast<const uint2*>(f + sB);
            const u32 vals[4] = {
                (va.x & 0xffffu) | (vb.x << 16),
                (va.x >> 16)     | (vb.x & 0xffff0000u),
                (va.y & 0xffffu) | (vb.y << 16),
                (va.y >> 16)     | (vb.y & 0xffff0000u)
            };
#pragma unroll
            for (int j = 0; j < 4; ++j){
                const int v = q16 * 4 + j;
                const int xv = (v ^ (v >> 4)) & 15;
                sh[v * 64 + (c2 & 3) + 4 * ((c2 >> 2) ^ xv)] = vals[j];
            }
        }
    } else {
        const float* f = (const float*)feat_;
        for (int it = 0; it < 4; ++it){
            const int i = it * 256 + t;
            const int c2 = i >> 4, q16 = i & 15;
            const size_t sA = ((size_t)(b * 128 + 2 * c2    )) * 110592 + rel + q16 * 4;
            const size_t sB = ((size_t)(b * 128 + 2 * c2 + 1)) * 110592 + rel + q16 * 4;
            const float4 a  = *reinterpret_cast<const float4*>(f + sA);
            const float4 bv = *reinterpret_cast<const float4*>(f + sB);
            const float av[4] = {a.x, a.y, a.z, a.w};
            const float bw[4] = {bv.x, bv.y, bv.z, bv.w};
#pragma unroll
            for (int j = 0; j < 4; ++j){
                const int v = q16 * 4 + j;
                const int xv = (v ^ (v >> 4)) & 15;
                sh[v * 64 + (c2 & 3) + 4 * ((c2 >> 2) ^ xv)] =
                    (u32)f2bf(av[j]) | ((u32)f2bf(bw[j]) << 16);
            }
        }
    }
    __syncthreads();
    u32* ft = reinterpret_cast<u32*>(featT);
    const size_t obase = (size_t)chunk * 4096;
#pragma unroll
    for (int k = 0; k < 4; ++k){
        const int G = k * 256 + t;                    // output 16B granules
        const int v = G >> 4, gr = G & 15;
        const int xv = (v ^ (v >> 4)) & 15;
        const uint4 val = *reinterpret_cast<const uint4*>(&sh[v * 64 + 4 * (gr ^ xv)]);
        *reinterpret_cast<uint4*>(ft + obase + (size_t)G * 4) = val;
    }
}

// ---------------- qk_all = qf @ M + bias, outer-product, 4q x 8c register tile.
// 512 blocks x 128 thr; block = 32 queries. LDS: M (swizzled) 64KB + qT 16KB = 80KB.
__global__ __launch_bounds__(128) void k_qk(const void* __restrict__ qf_,
                                            const float* __restrict__ M,
                                            const float* __restrict__ bias,
                                            float* __restrict__ qk_all,
                                            const int* __restrict__ flags){
    __shared__ float Msh[128 * 128];   // 64 KB, row-granule-swizzled
    __shared__ float qT[128 * 32];     // 16 KB: qT[e*32 + q]
    const int t = threadIdx.x;
    const int is_qf = flags[0];
    const int qbase = blockIdx.x * 32;
    {
        const float4* Mg4 = reinterpret_cast<const float4*>(M);
        float4* Ms4 = reinterpret_cast<float4*>(Msh);
        for (int i = t; i < 4096; i += 128)
            Ms4[(i & ~31) | gswz(i & 31)] = Mg4[i];
    }
    {
        const int q = t & 31;
        const int g0 = t >> 5;   // 0..3
#pragma unroll
        for (int p = 0; p < 8; ++p){
            const int gr = g0 * 8 + p;   // 0..31 e-granule
            float v[4];
            if (is_qf){
                const ushort4 a = *reinterpret_cast<const ushort4*>((const u16*)qf_ + (size_t)(qbase + q) * 128 + gr * 4);
                v[0] = bf2f(a.x); v[1] = bf2f(a.y); v[2] = bf2f(a.z); v[3] = bf2f(a.w);
            } else {
                const float4 a = *reinterpret_cast<const float4*>((const float*)qf_ + (size_t)(qbase + q) * 128 + gr * 4);
                v[0] = a.x; v[1] = a.y; v[2] = a.z; v[3] = a.w;
            }
#pragma unroll
            for (int j = 0; j < 4; ++j) qT[(gr * 4 + j) * 32 + q] = v[j];
        }
    }
    __syncthreads();
    const int co = t & 15;        // c-octet (8 channels)
    const int qa = t >> 4;        // q-quad 0..7
    const int gs0 = gswz(2 * co), gs1 = gswz(2 * co + 1);
    const f32x4* Ms4 = reinterpret_cast<const f32x4*>(Msh);
    const f32x4* Qs4 = reinterpret_cast<const f32x4*>(qT);
    const float4 b0 = *reinterpret_cast<const float4*>(bias + co * 8);
    const float4 b1 = *reinterpret_cast<const float4*>(bias + co * 8 + 4);
    const f32x2 bi0 = {b0.x, b0.y}, bi1 = {b0.z, b0.w};
    const f32x2 bi2 = {b1.x, b1.y}, bi3 = {b1.z, b1.w};
    f32x2 acc[4][4];
#pragma unroll
    for (int j = 0; j < 4; ++j){ acc[j][0] = bi0; acc[j][1] = bi1; acc[j][2] = bi2; acc[j][3] = bi3; }
#pragma unroll 4
    for (int e = 0; e < 128; ++e){
        const f32x4 qv = Qs4[e * 8 + qa];
        const f32x4 m0 = Ms4[e * 32 + gs0];
        const f32x4 m1 = Ms4[e * 32 + gs1];
        const f32x2 q01 = qv.xy, q23 = qv.zw;
        const f32x2 ma = m0.xy, mb = m0.zw, mc = m1.xy, md = m1.zw;
        pk_fma_b0(acc[0][0], q01, ma); pk_fma_b0(acc[0][1], q01, mb);
        pk_fma_b0(acc[0][2], q01, mc); pk_fma_b0(acc[0][3], q01, md);
        pk_fma_b1(acc[1][0], q01, ma); pk_fma_b1(acc[1][1], q01, mb);
        pk_fma_b1(acc[1][2], q01, mc); pk_fma_b1(acc[1][3], q01, md);
        pk_fma_b0(acc[2][0], q23, ma); pk_fma_b0(acc[2][1], q23, mb);
        pk_fma_b0(acc[2][2], q23, mc); pk_fma_b0(acc[2][3], q23, md);
        pk_fma_b1(acc[3][0], q23, ma); pk_fma_b1(acc[3][1], q23, mb);
        pk_fma_b1(acc[3][2], q23, mc); pk_fma_b1(acc[3][3], q23, md);
    }
#pragma unroll
    for (int j = 0; j < 4; ++j){
        const int q = qbase + qa * 4 + j;
        const f32x4 r0 = {acc[j][0].x, acc[j][0].y, acc[j][1].x, acc[j][1].y};
        const f32x4 r1 = {acc[j][2].x, acc[j][2].y, acc[j][3].x, acc[j][3].y};
        *reinterpret_cast<f32x4*>(qk_all + (size_t)q * 128 + co * 8)     = r0;
        *reinterpret_cast<f32x4*>(qk_all + (size_t)q * 128 + co * 8 + 4) = r1;
    }
}

// ---------------- attention gather from unpadded featT; g (fp32) to ws. 1 wave/query.
__global__ __launch_bounds__(256) void k_attn_feat(const u16* __restrict__ featT,
                                                   const float* __restrict__ qk_all,
                                                   const int* __restrict__ proj,
                                                   float* __restrict__ g,
                                                   const int* __restrict__ flags){
    const int lane = threadIdx.x & 63;
    const int q = blockIdx.x * 4 + (threadIdx.x >> 6);
    const int kg = lane >> 4, cl = lane & 15;
    const int b = q >> 13;
    const int p64 = flags[3];
    int pz, py, px; read_proj(proj, q, p64, pz, py, px);
    const float4* qp4 = reinterpret_cast<const float4*>(qk_all + (size_t)q * 128 + cl * 8);
    const float4 qA = qp4[0], qB = qp4[1];
    const f32x2 qA01 = {qA.x, qA.y}, qA23 = {qA.z, qA.w};
    const f32x2 qB01 = {qB.x, qB.y}, qB23 = {qB.z, qB.w};
    const u16* base = featT + (size_t)b * 14155776 + cl * 8;
    uint4 fr[7];
    float sc[7];
#pragma unroll
    for (int s = 0; s < 7; ++s){
        const int k = s * 4 + kg;
        uint4 v = make_uint4(0u, 0u, 0u, 0u);
        if (k < 27){
            const int dz = k / 9, r9 = k - dz * 9, dy = r9 / 3, dx = r9 - dy * 3;
            const int zz = min(max(pz - 1 + dz, 0), 47);
            const int yy = min(max(py - 1 + dy, 0), 47);
            const int xx = min(max(px - 1 + dx, 0), 47);
            v = *reinterpret_cast<const uint4*>(base + (size_t)(zz * 2304 + yy * 48 + xx) * 128);
        }
        fr[s] = v;
        const f32x2 f0 = {bflo(v.x), bfhi(v.x)};
        const f32x2 f1 = {bflo(v.y), bfhi(v.y)};
        const f32x2 f2 = {bflo(v.z), bfhi(v.z)};
        const f32x2 f3 = {bflo(v.w), bfhi(v.w)};
        f32x2 d2 = {0.f, 0.f};
        pk_fma(d2, qA01, f0); pk_fma(d2, qA23, f1);
        pk_fma(d2, qB01, f2); pk_fma(d2, qB23, f3);
        float t = d2.x + d2.y;
        t += __shfl_xor(t, 1, 64);
        t += __shfl_xor(t, 2, 64);
        t += __shfl_xor(t, 4, 64);
        t += __shfl_xor(t, 8, 64);
        sc[s] = (k < 27) ? t : -1e30f;
    }
    float mx = sc[0];
#pragma unroll
    for (int s = 1; s < 7; ++s) mx = fmaxf(mx, sc[s]);
    mx = fmaxf(mx, __shfl_xor(mx, 16, 64));
    mx = fmaxf(mx, __shfl_xor(mx, 32, 64));
    float e[7], Z = 0.f;
#pragma unroll
    for (int s = 0; s < 7; ++s){ e[s] = __expf(sc[s] - mx); Z += e[s]; }
    Z += __shfl_xor(Z, 16, 64);
    Z += __shfl_xor(Z, 32, 64);
    const float inv = 1.0f / Z;
    f32x2 w0 = {0.f,0.f}, w1 = {0.f,0.f}, w2 = {0.f,0.f}, w3 = {0.f,0.f};
#pragma unroll
    for (int s = 0; s < 7; ++s){
        const float a = e[s] * inv;
        const f32x2 aa = {a, a};
        const uint4 v = fr[s];
        const f32x2 f0 = {bflo(v.x), bfhi(v.x)};
        const f32x2 f1 = {bflo(v.y), bfhi(v.y)};
        const f32x2 f2 = {bflo(v.z), bfhi(v.z)};
        const f32x2 f3 = {bflo(v.w), bfhi(v.w)};
        pk_fma(w0, aa, f0); pk_fma(w1, aa, f1);
        pk_fma(w2, aa, f2); pk_fma(w3, aa, f3);
    }
    float w[8] = {w0.x, w0.y, w1.x, w1.y, w2.x, w2.y, w3.x, w3.y};
#pragma unroll
    for (int i = 0; i < 8; ++i){
        w[i] += __shfl_xor(w[i], 16, 64);
        w[i] += __shfl_xor(w[i], 32, 64);
    }
    if (kg == 0){
        float4 lo4; lo4.x = w[0]; lo4.y = w[1]; lo4.z = w[2]; lo4.w = w[3];
        float4 hi4; hi4.x = w[4]; hi4.y = w[5]; hi4.z = w[6]; hi4.w = w[7];
        float4* o = reinterpret_cast<float4*>(g + (size_t)q * 128 + cl * 8);
        o[0] = lo4; o[1] = hi4;
    }
}

// ---------------- tier-2: gather directly from feat (B,C,48^3)
__global__ __launch_bounds__(256) void k_attn_direct(const void* __restrict__ feat_,
                                                     const float* __restrict__ qk_all,
                                                     const int* __restrict__ proj,
                                                     float* __restrict__ g,
                                                     const int* __restrict__ flags){
    const int lane = threadIdx.x & 63;
    const int q = blockIdx.x * 4 + (threadIdx.x >> 6);
    const int kg = lane >> 4, cl = lane & 15;
    const int b = q >> 13;
    const int isbf = flags[1];
    const int p64 = flags[3];
    int pz, py, px; read_proj(proj, q, p64, pz, py, px);
    const float* qk = qk_all + (size_t)q * 128 + cl * 8;
    float qv[8];
#pragma unroll
    for (int i = 0; i < 8; ++i) qv[i] = qk[i];
    const size_t cbase = ((size_t)b * 128 + cl * 8) * 110592;
    float f[7][8];
    float sc[7];
#pragma unroll
    for (int s = 0; s < 7; ++s){
        const int k = s * 4 + kg;
#pragma unroll
        for (int i = 0; i < 8; ++i) f[s][i] = 0.f;
        if (k < 27){
            const int dz = k / 9, r9 = k - dz * 9, dy = r9 / 3, dx = r9 - dy * 3;
            const int zz = min(max(pz - 1 + dz, 0), 47);
            const int yy = min(max(py - 1 + dy, 0), 47);
            const int xx = min(max(px - 1 + dx, 0), 47);
            const size_t off = (size_t)zz * 2304 + yy * 48 + xx;
#pragma unroll
            for (int i = 0; i < 8; ++i) f[s][i] = ldf(feat_, cbase + (size_t)i * 110592 + off, isbf);
        }
        float t = 0.f;
#pragma unroll
        for (int i = 0; i < 8; ++i) t += qv[i] * f[s][i];
        t += __shfl_xor(t, 1, 64);
        t += __shfl_xor(t, 2, 64);
        t += __shfl_xor(t, 4, 64);
        t += __shfl_xor(t, 8, 64);
        sc[s] = (k < 27) ? t : -1e30f;
    }
    float mx = sc[0];
#pragma unroll
    for (int s = 1; s < 7; ++s) mx = fmaxf(mx, sc[s]);
    mx = fmaxf(mx, __shfl_xor(mx, 16, 64));
    mx = fmaxf(mx, __shfl_xor(mx, 32, 64));
    float e[7], Z = 0.f;
#pragma unroll
    for (int s = 0; s < 7; ++s){ e[s] = __expf(sc[s] - mx); Z += e[s]; }
    Z += __shfl_xor(Z, 16, 64);
    Z += __shfl_xor(Z, 32, 64);
    const float inv = 1.0f / Z;
    float w[8];
#pragma unroll
    for (int i = 0; i < 8; ++i) w[i] = 0.f;
#pragma unroll
    for (int s = 0; s < 7; ++s){
        const float a = e[s] * inv;
#pragma unroll
        for (int i = 0; i < 8; ++i) w[i] += a * f[s][i];
    }
#pragma unroll
    for (int i = 0; i < 8; ++i){
        w[i] += __shfl_xor(w[i], 16, 64);
        w[i] += __shfl_xor(w[i], 32, 64);
    }
    if (kg == 0){
        float4 lo4; lo4.x = w[0]; lo4.y = w[1]; lo4.z = w[2]; lo4.w = w[3];
        float4 hi4; hi4.x = w[4]; hi4.y = w[5]; hi4.z = w[6]; hi4.w = w[7];
        float4* o = reinterpret_cast<float4*>(g + (size_t)q * 128 + cl * 8);
        o[0] = lo4; o[1] = hi4;
    }
}

// ---------------- out = qf + vb + g @ W2, outer-product, 4q x 8c register tile.
__global__ __launch_bounds__(128) void k_out(const float* __restrict__ gbuf,
                                             const float* __restrict__ W2,
                                             const void* __restrict__ qf_,
                                             const void* __restrict__ vb_,
                                             float* __restrict__ out,
                                             const int* __restrict__ flags){
    __shared__ float Wsh[128 * 128];   // 64 KB, row-granule-swizzled
    __shared__ float gT[128 * 32];     // 16 KB: gT[c*32 + q]
    const int t = threadIdx.x;
    const int is_qf = flags[0];
    const int is_vb = flags[2];
    const int qbase = blockIdx.x * 32;
    {
        const float4* Wg4 = reinterpret_cast<const float4*>(W2);
        float4* Ws4 = reinterpret_cast<float4*>(Wsh);
        for (int i = t; i < 4096; i += 128)
            Ws4[(i & ~31) | gswz(i & 31)] = Wg4[i];
    }
    {
        const int q = t & 31;
        const int g0 = t >> 5;   // 0..3
#pragma unroll
        for (int p = 0; p < 8; ++p){
            const int gr = g0 * 8 + p;   // 0..31 c-granule
            const float4 a = *reinterpret_cast<const float4*>(gbuf + (size_t)(qbase + q) * 128 + gr * 4);
            gT[(gr * 4 + 0) * 32 + q] = a.x;
            gT[(gr * 4 + 1) * 32 + q] = a.y;
            gT[(gr * 4 + 2) * 32 + q] = a.z;
            gT[(gr * 4 + 3) * 32 + q] = a.w;
        }
    }
    __syncthreads();
    const int co = t & 15;        // d-octet
    const int qa = t >> 4;        // q-quad 0..7
    const int gs0 = gswz(2 * co), gs1 = gswz(2 * co + 1);
    const f32x4* Ws4 = reinterpret_cast<const f32x4*>(Wsh);
    const f32x4* Gs4 = reinterpret_cast<const f32x4*>(gT);
    float4 vb0, vb1;
    if (is_vb){
        const ushort4 v0 = *reinterpret_cast<const ushort4*>((const u16*)vb_ + co * 8);
        const ushort4 v1 = *reinterpret_cast<const ushort4*>((const u16*)vb_ + co * 8 + 4);
        vb0.x = bf2f(v0.x); vb0.y = bf2f(v0.y); vb0.z = bf2f(v0.z); vb0.w = bf2f(v0.w);
        vb1.x = bf2f(v1.x); vb1.y = bf2f(v1.y); vb1.z = bf2f(v1.z); vb1.w = bf2f(v1.w);
    } else {
        vb0 = *reinterpret_cast<const float4*>((const float*)vb_ + co * 8);
        vb1 = *reinterpret_cast<const float4*>((const float*)vb_ + co * 8 + 4);
    }
    const f32x2 bi0 = {vb0.x, vb0.y}, bi1 = {vb0.z, vb0.w};
    const f32x2 bi2 = {vb1.x, vb1.y}, bi3 = {vb1.z, vb1.w};
    f32x2 acc[4][4];
#pragma unroll
    for (int j = 0; j < 4; ++j){ acc[j][0] = bi0; acc[j][1] = bi1; acc[j][2] = bi2; acc[j][3] = bi3; }
#pragma unroll 4
    for (int c = 0; c < 128; ++c){
        const f32x4 gv = Gs4[c * 8 + qa];
        const f32x4 m0 = Ws4[c * 32 + gs0];
        const f32x4 m1 = Ws4[c * 32 + gs1];
        const f32x2 g01 = gv.xy, g23 = gv.zw;
        const f32x2 ma = m0.xy, mb = m0.zw, mc = m1.xy, md = m1.zw;
        pk_fma_b0(acc[0][0], g01, ma); pk_fma_b0(acc[0][1], g01, mb);
        pk_fma_b0(acc[0][2], g01, mc); pk_fma_b0(acc[0][3], g01, md);
        pk_fma_b1(acc[1][0], g01, ma); pk_fma_b1(acc[1][1], g01, mb);
        pk_fma_b1(acc[1][2], g01, mc); pk_fma_b1(acc[1][3], g01, md);
        pk_fma_b0(acc[2][0], g23, ma); pk_fma_b0(acc[2][1], g23, mb);
        pk_fma_b0(acc[2][2], g23, mc); pk_fma_b0(acc[2][3], g23, md);
        pk_fma_b1(acc[3][0], g23, ma); pk_fma_b1(acc[3][1], g23, mb);
        pk_fma_b1(acc[3][2], g23, mc); pk_fma_b1(acc[3][3], g23, md);
    }
#pragma unroll
    for (int j = 0; j < 4; ++j){
        const int q = qbase + qa * 4 + j;
        float4 r0, r1;
        if (is_qf){
            const ushort4 a0 = *reinterpret_cast<const ushort4*>((const u16*)qf_ + (size_t)q * 128 + co * 8);
            const ushort4 a1 = *reinterpret_cast<const ushort4*>((const u16*)qf_ + (size_t)q * 128 + co * 8 + 4);
            r0.x = bf2f(a0.x); r0.y = bf2f(a0.y); r0.z = bf2f(a0.z); r0.w = bf2f(a0.w);
            r1.x = bf2f(a1.x); r1.y = bf2f(a1.y); r1.z = bf2f(a1.z); r1.w = bf2f(a1.w);
        } else {
            r0 = *reinterpret_cast<const float4*>((const float*)qf_ + (size_t)q * 128 + co * 8);
            r1 = *reinterpret_cast<const float4*>((const float*)qf_ + (size_t)q * 128 + co * 8 + 4);
        }
        float4 o0, o1;
        o0.x = acc[j][0].x + r0.x; o0.y = acc[j][0].y + r0.y;
        o0.z = acc[j][1].x + r0.z; o0.w = acc[j][1].y + r0.w;
        o1.x = acc[j][2].x + r1.x; o1.y = acc[j][2].y + r1.y;
        o1.z = acc[j][3].x + r1.z; o1.w = acc[j][3].y + r1.w;
        *reinterpret_cast<float4*>(out + (size_t)q * 128 + co * 8)     = o0;
        *reinterpret_cast<float4*>(out + (size_t)q * 128 + co * 8 + 4) = o1;
    }
}

// ---------------- tier-3 fallback: the round-8 passing literal kernel
__global__ __launch_bounds__(128) void k_simple(const void* __restrict__ qf_,
                                                const void* __restrict__ feat_,
                                                const void* __restrict__ proj_,
                                                const void* __restrict__ qw_,
                                                const void* __restrict__ qb_,
                                                const void* __restrict__ kw_,
                                                const void* __restrict__ kb_,
                                                const void* __restrict__ vw_,
                                                const void* __restrict__ vb_,
                                                float* __restrict__ out){
    __shared__ float qfs[128];
    __shared__ float qs[128];
    __shared__ float ts[128];
    __shared__ float gs[128];
    __shared__ float ss4[27][4];
    __shared__ float aa[27];
    __shared__ float kbd[1];
    const int t = threadIdx.x;
    const int q = blockIdx.x;
    const int b = q >> 13;
    const int is_qf = detect_bf16(qf_);
    const int is_ft = detect_bf16(feat_);
    const int is_qw = detect_bf16(qw_);
    const int is_qb = detect_bf16(qb_);
    const int is_kw = detect_bf16(kw_);
    const int is_kb = detect_bf16(kb_);
    const int is_vw = detect_bf16(vw_);
    const int is_vb = detect_bf16(vb_);
    const int p64   = detect_i64((const int*)proj_);
    qfs[t] = ldf(qf_, (size_t)q * 128 + t, is_qf);
    __syncthreads();
    {
        float acc = ldf(qb_, t, is_qb);
        for (int e = 0; e < 128; ++e)
            acc += ldf(qw_, (size_t)t * 128 + e, is_qw) * qfs[e];
        qs[t] = acc;
    }
    __syncthreads();
    {
        float acc = 0.f;
        for (int d = 0; d < 128; ++d)
            acc += ldf(kw_, (size_t)d * 128 + t, is_kw) * qs[d];
        ts[t] = acc;
    }
    if (t == 0){
        float kd = 0.f;
        for (int d = 0; d < 128; ++d) kd += ldf(kb_, d, is_kb) * qs[d];
        kbd[0] = kd;
    }
    __syncthreads();
    int pz, py, px; read_proj((const int*)proj_, q, p64, pz, py, px);
    if (t < 108){
        const int k = t >> 2, part = t & 3;
        const int dz = k / 9, dy = (k / 3) % 3, dx = k % 3;
        const int zz = min(max(pz - 1 + dz, 0), 47);
        const int yy = min(max(py - 1 + dy, 0), 47);
        const int xx = min(max(px - 1 + dx, 0), 47);
        const size_t sp = (size_t)zz * 2304 + yy * 48 + xx;
        float s = 0.f;
        for (int c = part * 32; c < part * 32 + 32; ++c)
            s += ts[c] * ldf(feat_, ((size_t)b * 128 + c) * 110592 + sp, is_ft);
        ss4[k][part] = s;
    }
    __syncthreads();
    if (t == 0){
        float sc[27];
        float mx = -1e30f;
        for (int k = 0; k < 27; ++k){
            sc[k] = ss4[k][0] + ss4[k][1] + ss4[k][2] + ss4[k][3] + kbd[0];
            mx = fmaxf(mx, sc[k]);
        }
        float Z = 0.f;
        for (int k = 0; k < 27; ++k){ sc[k] = expf(sc[k] - mx); Z += sc[k]; }
        const float inv = 1.0f / Z;
        for (int k = 0; k < 27; ++k) aa[k] = sc[k] * inv;
    }
    __syncthreads();
    {
        float g = 0.f;
        const size_t cb = ((size_t)b * 128 + t) * 110592;
        for (int k = 0; k < 27; ++k){
            const int dz = k / 9, dy = (k / 3) % 3, dx = k % 3;
            const int zz = min(max(pz - 1 + dz, 0), 47);
            const int yy = min(max(py - 1 + dy, 0), 47);
            const int xx = min(max(px - 1 + dx, 0), 47);
            g += aa[k] * ldf(feat_, cb + (size_t)zz * 2304 + yy * 48 + xx, is_ft);
        }
        gs[t] = g;
    }
    __syncthreads();
    {
        float o = qfs[t] + ldf(vb_, t, is_vb);
        for (int c = 0; c < 128; ++c)
            o += ldf(vw_, (size_t)t * 128 + c, is_vw) * gs[c];
        out[(size_t)q * 128 + t] = o;
    }
}

extern "C" void kernel_launch(void* const* d_in, const int* in_sizes, int n_in,
                              void* d_out, int out_size, void* d_ws, size_t ws_size,
                              hipStream_t stream) {
    const void* qfeat = d_in[0];
    const void* feat  = d_in[1];
    const int*  proj  = (const int*)d_in[2];
    const void* qw = d_in[4];
    const void* qb = d_in[5];
    const void* kw = d_in[6];
    const void* kb = d_in[7];
    const void* vw = d_in[8];
    const void* vb = d_in[9];
    float* out = (float*)d_out;

    // ws layout
    char* wsb = (char*)d_ws;
    float* M      = (float*)(wsb);                //     65,536 B
    float* bias   = (float*)(wsb + 65536);        //        512 B
    int*   flags  = (int*)  (wsb + 66048);        //         64 B
    float* W2     = (float*)(wsb + 66112);        //     65,536 B
    float* qk_all = (float*)(wsb + 131648);       //  8,388,608 B
    float* g      = (float*)(wsb + 8520256);      //  8,388,608 B
    u16*   featT  = (u16*)  (wsb + 16908864);     // 56,623,104 B -> 73,531,968 total

    const int tier = (ws_size >= (size_t)73531968) ? 1
                   : (ws_size >= (size_t)16908864) ? 2 : 3;

    if (tier == 3){
        hipLaunchKernelGGL(k_simple, dim3(16384), dim3(128), 0, stream,
                           qfeat, feat, proj, qw, qb, kw, kb, vw, vb, out);
        return;
    }
    hipLaunchKernelGGL(k_prep, dim3(128), dim3(256), 0, stream,
                       qw, qb, kw, vw, qfeat, feat, proj, vb, M, bias, W2, flags);
    hipLaunchKernelGGL(k_qk,   dim3(512), dim3(128), 0, stream, qfeat, M, bias, qk_all, flags);
    if (tier == 1){
        hipLaunchKernelGGL(k_tr,        dim3(3456), dim3(256), 0, stream, feat, featT, flags);
        hipLaunchKernelGGL(k_attn_feat, dim3(4096), dim3(256), 0, stream, featT, qk_all, proj, g, flags);
    } else {
        hipLaunchKernelGGL(k_attn_direct, dim3(4096), dim3(256), 0, stream, feat, qk_all, proj, g, flags);
    }
    hipLaunchKernelGGL(k_out,  dim3(512), dim3(128), 0, stream, g, W2, qfeat, vb, out, flags);
}

// Round 5
// 291.311 us; speedup vs baseline: 1.0417x; 1.0417x over previous
//
#include <hip/hip_runtime.h>
#include <cstdint>

typedef unsigned short u16;
typedef unsigned int   u32;
typedef __attribute__((ext_vector_type(2))) float f32x2;
typedef __attribute__((ext_vector_type(4))) float f32x4;

__device__ __forceinline__ float bf2f(u16 u){ return __uint_as_float(((u32)u) << 16); }
__device__ __forceinline__ float bflo(u32 u){ return __uint_as_float(u << 16); }
__device__ __forceinline__ float bfhi(u32 u){ return __uint_as_float(u & 0xffff0000u); }
__device__ __forceinline__ u16 f2bf(float f){
    u32 x = __float_as_uint(f);
    u32 r = x + 0x7fffu + ((x >> 16) & 1u);
    return (u16)(r >> 16);
}
__device__ __forceinline__ int detect_bf16(const void* p){
    const u16* h = (const u16*)p;
    int hits = 0;
    for (int i = 0; i < 64; ++i){
        const int e = (h[2 * i] >> 7) & 0xFF;
        hits += (e >= 110 && e <= 140) ? 1 : 0;
    }
    return hits >= 40;
}
__device__ __forceinline__ int detect_i64(const int* p){
    int z = 0;
    for (int i = 0; i < 48; ++i) z += (p[2 * i + 1] == 0) ? 1 : 0;
    return z >= 40;
}
__device__ __forceinline__ float ldf(const void* p, size_t i, int isbf){
    return isbf ? bf2f(((const u16*)p)[i]) : ((const float*)p)[i];
}
__device__ __forceinline__ void read_proj(const int* proj, int q, int p64,
                                          int& pz, int& py, int& px){
    if (p64){
        pz = proj[(size_t)(q * 3 + 0) * 2];
        py = proj[(size_t)(q * 3 + 1) * 2];
        px = proj[(size_t)(q * 3 + 2) * 2];
    } else {
        pz = proj[q * 3 + 0]; py = proj[q * 3 + 1]; px = proj[q * 3 + 2];
    }
    pz = min(max(pz, 0), 47); py = min(max(py, 0), 47); px = min(max(px, 0), 47);
}

// packed fp32 FMA helpers (v_pk_fma_f32: D.lo=S0.lo*S1.lo+S2.lo, D.hi likewise)
// acc += broadcast(s.lo) * m
__device__ __forceinline__ void pk_fma_b0(f32x2& acc, const f32x2 s, const f32x2 m){
    asm("v_pk_fma_f32 %0, %1, %2, %0 op_sel:[0,0,0] op_sel_hi:[0,1,1]"
        : "+v"(acc) : "v"(s), "v"(m));
}
// acc += broadcast(s.hi) * m
__device__ __forceinline__ void pk_fma_b1(f32x2& acc, const f32x2 s, const f32x2 m){
    asm("v_pk_fma_f32 %0, %1, %2, %0 op_sel:[1,0,0] op_sel_hi:[1,1,1]"
        : "+v"(acc) : "v"(s), "v"(m));
}
// acc += a * b
__device__ __forceinline__ void pk_fma(f32x2& acc, const f32x2 a, const f32x2 b){
    asm("v_pk_fma_f32 %0, %1, %2, %0"
        : "+v"(acc) : "v"(a), "v"(b));
}

// ---------------- merged prep:
// blocks 0..63 : M[e][c] = sum_d qw[d][e]*kw[d][c]  (2 e's per block); block 0 also bias+flags
// blocks 64..127: W2[c][d] = vw[d][c]
__global__ __launch_bounds__(256) void k_prep(const void* __restrict__ qw_,
                                              const void* __restrict__ qb_,
                                              const void* __restrict__ kw_,
                                              const void* __restrict__ vw_,
                                              const void* __restrict__ qf_,
                                              const void* __restrict__ feat_,
                                              const int*  __restrict__ proj_,
                                              const void* __restrict__ vb_,
                                              float* __restrict__ M,
                                              float* __restrict__ bias,
                                              float* __restrict__ W2,
                                              int* __restrict__ flags){
    const int bid = blockIdx.x, t = threadIdx.x;
    if (bid < 64){
        if (bid == 0){
            if (t == 0)      flags[0] = detect_bf16(qf_);
            else if (t == 1) flags[1] = detect_bf16(feat_);
            else if (t == 2) flags[2] = detect_bf16(vb_);
            else if (t == 3) flags[3] = detect_i64(proj_);
        }
        const int e = bid * 2 + (t >> 7), c = t & 127;
        const int is_qw = detect_bf16(qw_), is_kw = detect_bf16(kw_);
        float acc = 0.f;
        for (int d = 0; d < 128; ++d)
            acc += ldf(kw_, (size_t)d * 128 + c, is_kw) * ldf(qw_, (size_t)d * 128 + e, is_qw);
        M[e * 128 + c] = acc;
        if (bid == 0 && t < 128){
            const int is_qb = detect_bf16(qb_);
            float ab = 0.f;
            for (int d = 0; d < 128; ++d)
                ab += ldf(kw_, (size_t)d * 128 + t, is_kw) * ldf(qb_, d, is_qb);
            bias[t] = ab;
        }
    } else {
        const int i = (bid - 64) * 256 + t;   // 0..16383
        const int c = i >> 7, d = i & 127;
        const int is_vw = detect_bf16(vw_);
        W2[c * 128 + d] = ldf(vw_, (size_t)d * 128 + c, is_vw);
    }
}

// ---------------- transpose (B,C,48,48,48) -> (B,48*48*48,C) bf16, NO padding.
__global__ __launch_bounds__(256) void k_tr(const void* __restrict__ feat_,
                                            u16* __restrict__ featT,
                                            const int* __restrict__ flags){
    __shared__ u32 sh[4096];        // 64 voxels * 64 u32 (channel pairs), swizzled
    const int t = threadIdx.x;
    const int isbf = flags[1];
    const int chunk = blockIdx.x;                     // 0..3455
    const int b = chunk / 1728;
    const size_t rel = (size_t)(chunk - b * 1728) * 64;
    if (isbf){
        const u16* f = (const u16*)feat_;
        for (int it = 0; it < 4; ++it){
            const int i = it * 256 + t;               // 0..1023
            const int c2 = i >> 4, q16 = i & 15;
            const size_t sA = ((size_t)(b * 128 + 2 * c2    )) * 110592 + rel + q16 * 4;
            const size_t sB = ((size_t)(b * 128 + 2 * c2 + 1)) * 110592 + rel + q16 * 4;
            const uint2 va = *reinterpret_cast<const uint2*>(f + sA);
            const uint2 vb = *reinterpret_cast<const uint2*>(f + sB);
            const u32 vals[4] = {
                (va.x & 0xffffu) | (vb.x << 16),
                (va.x >> 16)     | (vb.x & 0xffff0000u),
                (va.y & 0xffffu) | (vb.y << 16),
                (va.y >> 16)     | (vb.y & 0xffff0000u)
            };
#pragma unroll
            for (int j = 0; j < 4; ++j){
                const int v = q16 * 4 + j;
                const int xv = (v ^ (v >> 4)) & 15;
                sh[v * 64 + (c2 & 3) + 4 * ((c2 >> 2) ^ xv)] = vals[j];
            }
        }
    } else {
        const float* f = (const float*)feat_;
        for (int it = 0; it < 4; ++it){
            const int i = it * 256 + t;
            const int c2 = i >> 4, q16 = i & 15;
            const size_t sA = ((size_t)(b * 128 + 2 * c2    )) * 110592 + rel + q16 * 4;
            const size_t sB = ((size_t)(b * 128 + 2 * c2 + 1)) * 110592 + rel + q16 * 4;
            const float4 a  = *reinterpret_cast<const float4*>(f + sA);
            const float4 bv = *reinterpret_cast<const float4*>(f + sB);
            const float av[4] = {a.x, a.y, a.z, a.w};
            const float bw[4] = {bv.x, bv.y, bv.z, bv.w};
#pragma unroll
            for (int j = 0; j < 4; ++j){
                const int v = q16 * 4 + j;
                const int xv = (v ^ (v >> 4)) & 15;
                sh[v * 64 + (c2 & 3) + 4 * ((c2 >> 2) ^ xv)] =
                    (u32)f2bf(av[j]) | ((u32)f2bf(bw[j]) << 16);
            }
        }
    }
    __syncthreads();
    u32* ft = reinterpret_cast<u32*>(featT);
    const size_t obase = (size_t)chunk * 4096;
#pragma unroll
    for (int k = 0; k < 4; ++k){
        const int G = k * 256 + t;                    // output 16B granules
        const int v = G >> 4, gr = G & 15;
        const int xv = (v ^ (v >> 4)) & 15;
        const uint4 val = *reinterpret_cast<const uint4*>(&sh[v * 64 + 4 * (gr ^ xv)]);
        *reinterpret_cast<uint4*>(ft + obase + (size_t)G * 4) = val;
    }
}

// ---------------- qk_all = qf @ M + bias, outer-product, v_pk_fma_f32.
// 512 blocks x 256 thr; block = 32 queries. LDS: M 64KB + qT 16KB (2 blk/CU, 2 waves/SIMD).
__global__ __launch_bounds__(256) void k_qk(const void* __restrict__ qf_,
                                            const float* __restrict__ M,
                                            const float* __restrict__ bias,
                                            float* __restrict__ qk_all,
                                            const int* __restrict__ flags){
    __shared__ float Msh[128 * 128];   // 64 KB
    __shared__ float qT[128 * 32];     // 16 KB: qT[e*32 + q]
    const int t = threadIdx.x;
    const int is_qf = flags[0];
    const int qbase = blockIdx.x * 32;
    {
        const float4* Mg4 = reinterpret_cast<const float4*>(M);
        float4* Ms4 = reinterpret_cast<float4*>(Msh);
        for (int i = t; i < 4096; i += 256) Ms4[i] = Mg4[i];
    }
#pragma unroll
    for (int p = 0; p < 4; ++p){
        const int i = p * 256 + t;
        const int q = i & 31, gr = i >> 5;            // gr 0..31
        float v[4];
        if (is_qf){
            const ushort4 a = *reinterpret_cast<const ushort4*>((const u16*)qf_ + (size_t)(qbase + q) * 128 + gr * 4);
            v[0] = bf2f(a.x); v[1] = bf2f(a.y); v[2] = bf2f(a.z); v[3] = bf2f(a.w);
        } else {
            const float4 a = *reinterpret_cast<const float4*>((const float*)qf_ + (size_t)(qbase + q) * 128 + gr * 4);
            v[0] = a.x; v[1] = a.y; v[2] = a.z; v[3] = a.w;
        }
#pragma unroll
        for (int j = 0; j < 4; ++j) qT[(gr * 4 + j) * 32 + q] = v[j];
    }
    __syncthreads();
    const int g  = t & 31;        // channel granule (4 channels)
    const int qa = t >> 5;        // query quad 0..7
    const float4 b4 = *reinterpret_cast<const float4*>(bias + g * 4);
    const f32x2 bi01 = {b4.x, b4.y}, bi23 = {b4.z, b4.w};
    f32x2 a00 = bi01, a01 = bi23, a10 = bi01, a11 = bi23;
    f32x2 a20 = bi01, a21 = bi23, a30 = bi01, a31 = bi23;
#pragma unroll 4
    for (int e = 0; e < 128; ++e){
        const f32x4 qv = *reinterpret_cast<const f32x4*>(&qT[e * 32 + qa * 4]);
        const f32x4 mv = *reinterpret_cast<const f32x4*>(&Msh[e * 128 + g * 4]);
        const f32x2 q01 = qv.xy, q23 = qv.zw;
        const f32x2 m01 = mv.xy, m23 = mv.zw;
        pk_fma_b0(a00, q01, m01); pk_fma_b0(a01, q01, m23);
        pk_fma_b1(a10, q01, m01); pk_fma_b1(a11, q01, m23);
        pk_fma_b0(a20, q23, m01); pk_fma_b0(a21, q23, m23);
        pk_fma_b1(a30, q23, m01); pk_fma_b1(a31, q23, m23);
    }
    const f32x4 r0 = {a00.x, a00.y, a01.x, a01.y};
    const f32x4 r1 = {a10.x, a10.y, a11.x, a11.y};
    const f32x4 r2 = {a20.x, a20.y, a21.x, a21.y};
    const f32x4 r3 = {a30.x, a30.y, a31.x, a31.y};
    *reinterpret_cast<f32x4*>(qk_all + (size_t)(qbase + qa * 4 + 0) * 128 + g * 4) = r0;
    *reinterpret_cast<f32x4*>(qk_all + (size_t)(qbase + qa * 4 + 1) * 128 + g * 4) = r1;
    *reinterpret_cast<f32x4*>(qk_all + (size_t)(qbase + qa * 4 + 2) * 128 + g * 4) = r2;
    *reinterpret_cast<f32x4*>(qk_all + (size_t)(qbase + qa * 4 + 3) * 128 + g * 4) = r3;
}

// ---------------- attention gather from unpadded featT; g (fp32) to ws. 1 wave/query.
__global__ __launch_bounds__(256) void k_attn_feat(const u16* __restrict__ featT,
                                                   const float* __restrict__ qk_all,
                                                   const int* __restrict__ proj,
                                                   float* __restrict__ g,
                                                   const int* __restrict__ flags){
    const int lane = threadIdx.x & 63;
    const int q = blockIdx.x * 4 + (threadIdx.x >> 6);
    const int kg = lane >> 4, cl = lane & 15;
    const int b = q >> 13;
    const int p64 = flags[3];
    int pz, py, px; read_proj(proj, q, p64, pz, py, px);
    const float4* qp4 = reinterpret_cast<const float4*>(qk_all + (size_t)q * 128 + cl * 8);
    const float4 qA = qp4[0], qB = qp4[1];
    const f32x2 qA01 = {qA.x, qA.y}, qA23 = {qA.z, qA.w};
    const f32x2 qB01 = {qB.x, qB.y}, qB23 = {qB.z, qB.w};
    const u16* base = featT + (size_t)b * 14155776 + cl * 8;
    uint4 fr[7];
    float sc[7];
#pragma unroll
    for (int s = 0; s < 7; ++s){
        const int k = s * 4 + kg;
        uint4 v = make_uint4(0u, 0u, 0u, 0u);
        if (k < 27){
            const int dz = k / 9, r9 = k - dz * 9, dy = r9 / 3, dx = r9 - dy * 3;
            const int zz = min(max(pz - 1 + dz, 0), 47);
            const int yy = min(max(py - 1 + dy, 0), 47);
            const int xx = min(max(px - 1 + dx, 0), 47);
            v = *reinterpret_cast<const uint4*>(base + (size_t)(zz * 2304 + yy * 48 + xx) * 128);
        }
        fr[s] = v;
        const f32x2 f0 = {bflo(v.x), bfhi(v.x)};
        const f32x2 f1 = {bflo(v.y), bfhi(v.y)};
        const f32x2 f2 = {bflo(v.z), bfhi(v.z)};
        const f32x2 f3 = {bflo(v.w), bfhi(v.w)};
        f32x2 d2 = {0.f, 0.f};
        pk_fma(d2, qA01, f0); pk_fma(d2, qA23, f1);
        pk_fma(d2, qB01, f2); pk_fma(d2, qB23, f3);
        float t = d2.x + d2.y;
        t += __shfl_xor(t, 1, 64);
        t += __shfl_xor(t, 2, 64);
        t += __shfl_xor(t, 4, 64);
        t += __shfl_xor(t, 8, 64);
        sc[s] = (k < 27) ? t : -1e30f;
    }
    float mx = sc[0];
#pragma unroll
    for (int s = 1; s < 7; ++s) mx = fmaxf(mx, sc[s]);
    mx = fmaxf(mx, __shfl_xor(mx, 16, 64));
    mx = fmaxf(mx, __shfl_xor(mx, 32, 64));
    float e[7], Z = 0.f;
#pragma unroll
    for (int s = 0; s < 7; ++s){ e[s] = __expf(sc[s] - mx); Z += e[s]; }
    Z += __shfl_xor(Z, 16, 64);
    Z += __shfl_xor(Z, 32, 64);
    const float inv = 1.0f / Z;
    f32x2 w0 = {0.f,0.f}, w1 = {0.f,0.f}, w2 = {0.f,0.f}, w3 = {0.f,0.f};
#pragma unroll
    for (int s = 0; s < 7; ++s){
        const float a = e[s] * inv;
        const f32x2 aa = {a, a};
        const uint4 v = fr[s];
        const f32x2 f0 = {bflo(v.x), bfhi(v.x)};
        const f32x2 f1 = {bflo(v.y), bfhi(v.y)};
        const f32x2 f2 = {bflo(v.z), bfhi(v.z)};
        const f32x2 f3 = {bflo(v.w), bfhi(v.w)};
        pk_fma(w0, aa, f0); pk_fma(w1, aa, f1);
        pk_fma(w2, aa, f2); pk_fma(w3, aa, f3);
    }
    float w[8] = {w0.x, w0.y, w1.x, w1.y, w2.x, w2.y, w3.x, w3.y};
#pragma unroll
    for (int i = 0; i < 8; ++i){
        w[i] += __shfl_xor(w[i], 16, 64);
        w[i] += __shfl_xor(w[i], 32, 64);
    }
    if (kg == 0){
        float4 lo4; lo4.x = w[0]; lo4.y = w[1]; lo4.z = w[2]; lo4.w = w[3];
        float4 hi4; hi4.x = w[4]; hi4.y = w[5]; hi4.z = w[6]; hi4.w = w[7];
        float4* o = reinterpret_cast<float4*>(g + (size_t)q * 128 + cl * 8);
        o[0] = lo4; o[1] = hi4;
    }
}

// ---------------- tier-2: gather directly from feat (B,C,48^3)
__global__ __launch_bounds__(256) void k_attn_direct(const void* __restrict__ feat_,
                                                     const float* __restrict__ qk_all,
                                                     const int* __restrict__ proj,
                                                     float* __restrict__ g,
                                                     const int* __restrict__ flags){
    const int lane = threadIdx.x & 63;
    const int q = blockIdx.x * 4 + (threadIdx.x >> 6);
    const int kg = lane >> 4, cl = lane & 15;
    const int b = q >> 13;
    const int isbf = flags[1];
    const int p64 = flags[3];
    int pz, py, px; read_proj(proj, q, p64, pz, py, px);
    const float* qk = qk_all + (size_t)q * 128 + cl * 8;
    float qv[8];
#pragma unroll
    for (int i = 0; i < 8; ++i) qv[i] = qk[i];
    const size_t cbase = ((size_t)b * 128 + cl * 8) * 110592;
    float f[7][8];
    float sc[7];
#pragma unroll
    for (int s = 0; s < 7; ++s){
        const int k = s * 4 + kg;
#pragma unroll
        for (int i = 0; i < 8; ++i) f[s][i] = 0.f;
        if (k < 27){
            const int dz = k / 9, r9 = k - dz * 9, dy = r9 / 3, dx = r9 - dy * 3;
            const int zz = min(max(pz - 1 + dz, 0), 47);
            const int yy = min(max(py - 1 + dy, 0), 47);
            const int xx = min(max(px - 1 + dx, 0), 47);
            const size_t off = (size_t)zz * 2304 + yy * 48 + xx;
#pragma unroll
            for (int i = 0; i < 8; ++i) f[s][i] = ldf(feat_, cbase + (size_t)i * 110592 + off, isbf);
        }
        float t = 0.f;
#pragma unroll
        for (int i = 0; i < 8; ++i) t += qv[i] * f[s][i];
        t += __shfl_xor(t, 1, 64);
        t += __shfl_xor(t, 2, 64);
        t += __shfl_xor(t, 4, 64);
        t += __shfl_xor(t, 8, 64);
        sc[s] = (k < 27) ? t : -1e30f;
    }
    float mx = sc[0];
#pragma unroll
    for (int s = 1; s < 7; ++s) mx = fmaxf(mx, sc[s]);
    mx = fmaxf(mx, __shfl_xor(mx, 16, 64));
    mx = fmaxf(mx, __shfl_xor(mx, 32, 64));
    float e[7], Z = 0.f;
#pragma unroll
    for (int s = 0; s < 7; ++s){ e[s] = __expf(sc[s] - mx); Z += e[s]; }
    Z += __shfl_xor(Z, 16, 64);
    Z += __shfl_xor(Z, 32, 64);
    const float inv = 1.0f / Z;
    float w[8];
#pragma unroll
    for (int i = 0; i < 8; ++i) w[i] = 0.f;
#pragma unroll
    for (int s = 0; s < 7; ++s){
        const float a = e[s] * inv;
#pragma unroll
        for (int i = 0; i < 8; ++i) w[i] += a * f[s][i];
    }
#pragma unroll
    for (int i = 0; i < 8; ++i){
        w[i] += __shfl_xor(w[i], 16, 64);
        w[i] += __shfl_xor(w[i], 32, 64);
    }
    if (kg == 0){
        float4 lo4; lo4.x = w[0]; lo4.y = w[1]; lo4.z = w[2]; lo4.w = w[3];
        float4 hi4; hi4.x = w[4]; hi4.y = w[5]; hi4.z = w[6]; hi4.w = w[7];
        float4* o = reinterpret_cast<float4*>(g + (size_t)q * 128 + cl * 8);
        o[0] = lo4; o[1] = hi4;
    }
}

// ---------------- out = qf + vb + g @ W2, outer-product, v_pk_fma_f32.
__global__ __launch_bounds__(256) void k_out(const float* __restrict__ gbuf,
                                             const float* __restrict__ W2,
                                             const void* __restrict__ qf_,
                                             const void* __restrict__ vb_,
                                             float* __restrict__ out,
                                             const int* __restrict__ flags){
    __shared__ float Wsh[128 * 128];   // 64 KB
    __shared__ float gT[128 * 32];     // 16 KB: gT[c*32 + q]
    const int t = threadIdx.x;
    const int is_qf = flags[0];
    const int is_vb = flags[2];
    const int qbase = blockIdx.x * 32;
    {
        const float4* Wg4 = reinterpret_cast<const float4*>(W2);
        float4* Ws4 = reinterpret_cast<float4*>(Wsh);
        for (int i = t; i < 4096; i += 256) Ws4[i] = Wg4[i];
    }
#pragma unroll
    for (int p = 0; p < 4; ++p){
        const int i = p * 256 + t;
        const int q = i & 31, gr = i >> 5;
        const float4 a = *reinterpret_cast<const float4*>(gbuf + (size_t)(qbase + q) * 128 + gr * 4);
        gT[(gr * 4 + 0) * 32 + q] = a.x;
        gT[(gr * 4 + 1) * 32 + q] = a.y;
        gT[(gr * 4 + 2) * 32 + q] = a.z;
        gT[(gr * 4 + 3) * 32 + q] = a.w;
    }
    __syncthreads();
    const int g  = t & 31;        // d granule
    const int qa = t >> 5;
    float4 vb4;
    if (is_vb){
        const ushort4 v = *reinterpret_cast<const ushort4*>((const u16*)vb_ + g * 4);
        vb4.x = bf2f(v.x); vb4.y = bf2f(v.y); vb4.z = bf2f(v.z); vb4.w = bf2f(v.w);
    } else {
        vb4 = *reinterpret_cast<const float4*>((const float*)vb_ + g * 4);
    }
    const f32x2 bi01 = {vb4.x, vb4.y}, bi23 = {vb4.z, vb4.w};
    f32x2 a00 = bi01, a01 = bi23, a10 = bi01, a11 = bi23;
    f32x2 a20 = bi01, a21 = bi23, a30 = bi01, a31 = bi23;
#pragma unroll 4
    for (int c = 0; c < 128; ++c){
        const f32x4 gv = *reinterpret_cast<const f32x4*>(&gT[c * 32 + qa * 4]);
        const f32x4 mv = *reinterpret_cast<const f32x4*>(&Wsh[c * 128 + g * 4]);
        const f32x2 g01 = gv.xy, g23 = gv.zw;
        const f32x2 m01 = mv.xy, m23 = mv.zw;
        pk_fma_b0(a00, g01, m01); pk_fma_b0(a01, g01, m23);
        pk_fma_b1(a10, g01, m01); pk_fma_b1(a11, g01, m23);
        pk_fma_b0(a20, g23, m01); pk_fma_b0(a21, g23, m23);
        pk_fma_b1(a30, g23, m01); pk_fma_b1(a31, g23, m23);
    }
    float4 accs[4];
    accs[0] = make_float4(a00.x, a00.y, a01.x, a01.y);
    accs[1] = make_float4(a10.x, a10.y, a11.x, a11.y);
    accs[2] = make_float4(a20.x, a20.y, a21.x, a21.y);
    accs[3] = make_float4(a30.x, a30.y, a31.x, a31.y);
#pragma unroll
    for (int j = 0; j < 4; ++j){
        const int q = qbase + qa * 4 + j;
        float4 acc = accs[j];
        float4 r;
        if (is_qf){
            const ushort4 a = *reinterpret_cast<const ushort4*>((const u16*)qf_ + (size_t)q * 128 + g * 4);
            r.x = bf2f(a.x); r.y = bf2f(a.y); r.z = bf2f(a.z); r.w = bf2f(a.w);
        } else {
            r = *reinterpret_cast<const float4*>((const float*)qf_ + (size_t)q * 128 + g * 4);
        }
        acc.x += r.x; acc.y += r.y; acc.z += r.z; acc.w += r.w;
        *reinterpret_cast<float4*>(out + (size_t)q * 128 + g * 4) = acc;
    }
}

// ---------------- tier-3 fallback: the round-8 passing literal kernel
__global__ __launch_bounds__(128) void k_simple(const void* __restrict__ qf_,
                                                const void* __restrict__ feat_,
                                                const void* __restrict__ proj_,
                                                const void* __restrict__ qw_,
                                                const void* __restrict__ qb_,
                                                const void* __restrict__ kw_,
                                                const void* __restrict__ kb_,
                                                const void* __restrict__ vw_,
                                                const void* __restrict__ vb_,
                                                float* __restrict__ out){
    __shared__ float qfs[128];
    __shared__ float qs[128];
    __shared__ float ts[128];
    __shared__ float gs[128];
    __shared__ float ss4[27][4];
    __shared__ float aa[27];
    __shared__ float kbd[1];
    const int t = threadIdx.x;
    const int q = blockIdx.x;
    const int b = q >> 13;
    const int is_qf = detect_bf16(qf_);
    const int is_ft = detect_bf16(feat_);
    const int is_qw = detect_bf16(qw_);
    const int is_qb = detect_bf16(qb_);
    const int is_kw = detect_bf16(kw_);
    const int is_kb = detect_bf16(kb_);
    const int is_vw = detect_bf16(vw_);
    const int is_vb = detect_bf16(vb_);
    const int p64   = detect_i64((const int*)proj_);
    qfs[t] = ldf(qf_, (size_t)q * 128 + t, is_qf);
    __syncthreads();
    {
        float acc = ldf(qb_, t, is_qb);
        for (int e = 0; e < 128; ++e)
            acc += ldf(qw_, (size_t)t * 128 + e, is_qw) * qfs[e];
        qs[t] = acc;
    }
    __syncthreads();
    {
        float acc = 0.f;
        for (int d = 0; d < 128; ++d)
            acc += ldf(kw_, (size_t)d * 128 + t, is_kw) * qs[d];
        ts[t] = acc;
    }
    if (t == 0){
        float kd = 0.f;
        for (int d = 0; d < 128; ++d) kd += ldf(kb_, d, is_kb) * qs[d];
        kbd[0] = kd;
    }
    __syncthreads();
    int pz, py, px; read_proj((const int*)proj_, q, p64, pz, py, px);
    if (t < 108){
        const int k = t >> 2, part = t & 3;
        const int dz = k / 9, dy = (k / 3) % 3, dx = k % 3;
        const int zz = min(max(pz - 1 + dz, 0), 47);
        const int yy = min(max(py - 1 + dy, 0), 47);
        const int xx = min(max(px - 1 + dx, 0), 47);
        const size_t sp = (size_t)zz * 2304 + yy * 48 + xx;
        float s = 0.f;
        for (int c = part * 32; c < part * 32 + 32; ++c)
            s += ts[c] * ldf(feat_, ((size_t)b * 128 + c) * 110592 + sp, is_ft);
        ss4[k][part] = s;
    }
    __syncthreads();
    if (t == 0){
        float sc[27];
        float mx = -1e30f;
        for (int k = 0; k < 27; ++k){
            sc[k] = ss4[k][0] + ss4[k][1] + ss4[k][2] + ss4[k][3] + kbd[0];
            mx = fmaxf(mx, sc[k]);
        }
        float Z = 0.f;
        for (int k = 0; k < 27; ++k){ sc[k] = expf(sc[k] - mx); Z += sc[k]; }
        const float inv = 1.0f / Z;
        for (int k = 0; k < 27; ++k) aa[k] = sc[k] * inv;
    }
    __syncthreads();
    {
        float g = 0.f;
        const size_t cb = ((size_t)b * 128 + t) * 110592;
        for (int k = 0; k < 27; ++k){
            const int dz = k / 9, dy = (k / 3) % 3, dx = k % 3;
            const int zz = min(max(pz - 1 + dz, 0), 47);
            const int yy = min(max(py - 1 + dy, 0), 47);
            const int xx = min(max(px - 1 + dx, 0), 47);
            g += aa[k] * ldf(feat_, cb + (size_t)zz * 2304 + yy * 48 + xx, is_ft);
        }
        gs[t] = g;
    }
    __syncthreads();
    {
        float o = qfs[t] + ldf(vb_, t, is_vb);
        for (int c = 0; c < 128; ++c)
            o += ldf(vw_, (size_t)t * 128 + c, is_vw) * gs[c];
        out[(size_t)q * 128 + t] = o;
    }
}

extern "C" void kernel_launch(void* const* d_in, const int* in_sizes, int n_in,
                              void* d_out, int out_size, void* d_ws, size_t ws_size,
                              hipStream_t stream) {
    const void* qfeat = d_in[0];
    const void* feat  = d_in[1];
    const int*  proj  = (const int*)d_in[2];
    const void* qw = d_in[4];
    const void* qb = d_in[5];
    const void* kw = d_in[6];
    const void* kb = d_in[7];
    const void* vw = d_in[8];
    const void* vb = d_in[9];
    float* out = (float*)d_out;

    // ws layout
    char* wsb = (char*)d_ws;
    float* M      = (float*)(wsb);                //     65,536 B
    float* bias   = (float*)(wsb + 65536);        //        512 B
    int*   flags  = (int*)  (wsb + 66048);        //         64 B
    float* W2     = (float*)(wsb + 66112);        //     65,536 B
    float* qk_all = (float*)(wsb + 131648);       //  8,388,608 B
    float* g      = (float*)(wsb + 8520256);      //  8,388,608 B
    u16*   featT  = (u16*)  (wsb + 16908864);     // 56,623,104 B -> 73,531,968 total

    const int tier = (ws_size >= (size_t)73531968) ? 1
                   : (ws_size >= (size_t)16908864) ? 2 : 3;

    if (tier == 3){
        hipLaunchKernelGGL(k_simple, dim3(16384), dim3(128), 0, stream,
                           qfeat, feat, proj, qw, qb, kw, kb, vw, vb, out);
        return;
    }
    hipLaunchKernelGGL(k_prep, dim3(128), dim3(256), 0, stream,
                       qw, qb, kw, vw, qfeat, feat, proj, vb, M, bias, W2, flags);
    hipLaunchKernelGGL(k_qk,   dim3(512), dim3(256), 0, stream, qfeat, M, bias, qk_all, flags);
    if (tier == 1){
        hipLaunchKernelGGL(k_tr,        dim3(3456), dim3(256), 0, stream, feat, featT, flags);
        hipLaunchKernelGGL(k_attn_feat, dim3(4096), dim3(256), 0, stream, featT, qk_all, proj, g, flags);
    } else {
        hipLaunchKernelGGL(k_attn_direct, dim3(4096), dim3(256), 0, stream, feat, qk_all, proj, g, flags);
    }
    hipLaunchKernelGGL(k_out,  dim3(512), dim3(256), 0, stream, g, W2, qfeat, vb, out, flags);
}